// Round 1
// baseline (410.474 us; speedup 1.0000x reference)
//
#include <hip/hip_runtime.h>
#include <hip/hip_bf16.h>

#define S_LEN 2048
#define DM 1024
#define NH 16
#define DH 64
#define MTOK 4096

typedef __attribute__((ext_vector_type(8))) __bf16 bf16x8;
typedef __attribute__((ext_vector_type(4))) float f32x4;
typedef unsigned short u16;

__device__ __forceinline__ u16 f2bf(float f) {
  union { float f; unsigned u; } a; a.f = f;
  unsigned u = a.u;
  u += 0x7fffu + ((u >> 16) & 1u);   // RNE
  return (u16)(u >> 16);
}

__device__ __forceinline__ bf16x8 ld_bf8(const u16* p) {
  return *reinterpret_cast<const bf16x8*>(p);
}

// ---------------- fp32 -> bf16 convert ----------------
__global__ void k_convert(const float* __restrict__ src, u16* __restrict__ dst, int n4) {
  int i = blockIdx.x * blockDim.x + threadIdx.x;
  int stride = gridDim.x * blockDim.x;
  for (; i < n4; i += stride) {
    float4 v = reinterpret_cast<const float4*>(src)[i];
    ushort4 o;
    o.x = f2bf(v.x); o.y = f2bf(v.y); o.z = f2bf(v.z); o.w = f2bf(v.w);
    reinterpret_cast<ushort4*>(dst)[i] = o;
  }
}

// ---------------- bf16 GEMM, B^T weights: C = A @ W^T + bias ----------------
// A [M=4096][K=1024] bf16 row-major, Bw [N=1024][K=1024] bf16 row-major.
// MODE 0: bf16 out scattered to [B*H][S][DH]   (Q, K buffers)
// MODE 1: bf16 out scattered to [B*H][DH][S]   (V transposed)
// MODE 2: f32 out row-major [M][N]             (final output)
template<int MODE>
__global__ __launch_bounds__(256) void k_gemm(
    const u16* __restrict__ A, const u16* __restrict__ Bw,
    const float* __restrict__ bias, void* __restrict__ dst) {
  constexpr int K = DM;
  __shared__ u16 As[128 * 32];
  __shared__ u16 Bs[128 * 32];
  const int tid = threadIdx.x;
  const int lane = tid & 63;
  const int wid = tid >> 6;
  const int wm = wid >> 1, wn = wid & 1;
  const int bm = blockIdx.x * 128;
  const int bn = blockIdx.y * 128;
  const int r0 = tid >> 2;           // 0..63
  const int c0 = (tid & 3) * 8;      // bf16 offset within 32-wide row
  const int fr = lane & 15;
  const int fk = (lane >> 4) * 8;

  f32x4 acc[4][4] = {};

  const u16* ga = A + (size_t)(bm + r0) * K + c0;
  const u16* gb = Bw + (size_t)(bn + r0) * K + c0;

  for (int kt = 0; kt < K; kt += 32) {
    __syncthreads();
    __builtin_amdgcn_global_load_lds(
        (const __attribute__((address_space(1))) void*)(ga + kt),
        (__attribute__((address_space(3))) void*)(&As[r0 * 32 + c0]), 16, 0, 0);
    __builtin_amdgcn_global_load_lds(
        (const __attribute__((address_space(1))) void*)(ga + (size_t)64 * K + kt),
        (__attribute__((address_space(3))) void*)(&As[(r0 + 64) * 32 + c0]), 16, 0, 0);
    __builtin_amdgcn_global_load_lds(
        (const __attribute__((address_space(1))) void*)(gb + kt),
        (__attribute__((address_space(3))) void*)(&Bs[r0 * 32 + c0]), 16, 0, 0);
    __builtin_amdgcn_global_load_lds(
        (const __attribute__((address_space(1))) void*)(gb + (size_t)64 * K + kt),
        (__attribute__((address_space(3))) void*)(&Bs[(r0 + 64) * 32 + c0]), 16, 0, 0);
    __syncthreads();
    bf16x8 af[4], bfr[4];
#pragma unroll
    for (int m = 0; m < 4; ++m) af[m] = ld_bf8(&As[(wm * 64 + m * 16 + fr) * 32 + fk]);
#pragma unroll
    for (int n = 0; n < 4; ++n) bfr[n] = ld_bf8(&Bs[(wn * 64 + n * 16 + fr) * 32 + fk]);
#pragma unroll
    for (int m = 0; m < 4; ++m)
#pragma unroll
      for (int n = 0; n < 4; ++n)
        acc[m][n] = __builtin_amdgcn_mfma_f32_16x16x32_bf16(af[m], bfr[n], acc[m][n], 0, 0, 0);
  }

  // C/D layout: col = lane&15, row = (lane>>4)*4 + reg
  const int cr = (lane >> 4) * 4;
  const int cc = lane & 15;
#pragma unroll
  for (int m = 0; m < 4; ++m) {
#pragma unroll
    for (int n = 0; n < 4; ++n) {
      const int colg = bn + wn * 64 + n * 16 + cc;
      const float bv = bias[colg];
      const int rbase = bm + wm * 64 + m * 16 + cr;
      if (MODE == 2) {
        float* o = (float*)dst;
#pragma unroll
        for (int r = 0; r < 4; ++r)
          o[(size_t)(rbase + r) * DM + colg] = acc[m][n][r] + bv;
      } else if (MODE == 0) {
        u16* o = (u16*)dst;
        const int h = colg >> 6, d = colg & 63;
#pragma unroll
        for (int r = 0; r < 4; ++r) {
          const int tok = rbase + r;
          const int b = tok >> 11, s = tok & 2047;
          o[(((size_t)(b * NH + h) * S_LEN) + s) * DH + d] = f2bf(acc[m][n][r] + bv);
        }
      } else {
        u16* o = (u16*)dst;
        const int h = colg >> 6, d = colg & 63;
        const int tok = rbase;
        const int b = tok >> 11, s = tok & 2047;
        ushort4 pk;
        pk.x = f2bf(acc[m][n][0] + bv);
        pk.y = f2bf(acc[m][n][1] + bv);
        pk.z = f2bf(acc[m][n][2] + bv);
        pk.w = f2bf(acc[m][n][3] + bv);
        *reinterpret_cast<ushort4*>(&o[(((size_t)(b * NH + h) * DH) + d) * S_LEN + s]) = pk;
      }
    }
  }
}

// ---------------- fused flash attention ----------------
// Qb,Kb: [B*H][S][64] bf16; Vt: [B*H][64][S] bf16; bias [H][S][S] f32; mask [B][S][S] i32
// ctx out: [B*S][1024] bf16 (token-major for output GEMM)
__global__ __launch_bounds__(256) void k_attn(
    const u16* __restrict__ Qb, const u16* __restrict__ Kb, const u16* __restrict__ Vt,
    const float* __restrict__ bias, const int* __restrict__ mask,
    u16* __restrict__ ctx) {
  __shared__ u16 P[4][16][72];   // per-wave P tile, padded (144B row stride, 16B aligned)
  const int tid = threadIdx.x;
  const int lane = tid & 63;
  const int w = tid >> 6;
  const int qt = blockIdx.x >> 1;
  const int b = blockIdx.x & 1;
  const int h = blockIdx.y;
  const int bh = b * NH + h;
  const int fr = lane & 15;
  const int fk = (lane >> 4) * 8;
  const int cr = (lane >> 4) * 4;
  const int cc = lane & 15;
  const int q0 = qt * 64 + w * 16;

  const u16* Qp = Qb + (size_t)bh * S_LEN * DH;
  const u16* Kp = Kb + (size_t)bh * S_LEN * DH;
  const u16* Vp = Vt + (size_t)bh * DH * S_LEN;
  const float* bp = bias + (size_t)h * S_LEN * S_LEN;
  const int* mp = mask + (size_t)b * S_LEN * S_LEN;

  bf16x8 qf[2];
  qf[0] = ld_bf8(&Qp[(size_t)(q0 + fr) * DH + fk]);
  qf[1] = ld_bf8(&Qp[(size_t)(q0 + fr) * DH + 32 + fk]);

  f32x4 cacc[4] = {};
  float m_run[4] = {-1e30f, -1e30f, -1e30f, -1e30f};
  float l_run[4] = {0.f, 0.f, 0.f, 0.f};

  for (int kt = 0; kt < S_LEN; kt += 64) {
    // ---- scores = Q K^T (fragments straight from global; L2-resident K) ----
    f32x4 sc[4] = {};
#pragma unroll
    for (int nb = 0; nb < 4; ++nb) {
      bf16x8 kf0 = ld_bf8(&Kp[(size_t)(kt + nb * 16 + fr) * DH + fk]);
      bf16x8 kf1 = ld_bf8(&Kp[(size_t)(kt + nb * 16 + fr) * DH + 32 + fk]);
      sc[nb] = __builtin_amdgcn_mfma_f32_16x16x32_bf16(qf[0], kf0, sc[nb], 0, 0, 0);
      sc[nb] = __builtin_amdgcn_mfma_f32_16x16x32_bf16(qf[1], kf1, sc[nb], 0, 0, 0);
    }
    // ---- scale + position_bias + mask ----
#pragma unroll
    for (int nb = 0; nb < 4; ++nb) {
      const int kg = kt + nb * 16 + cc;
#pragma unroll
      for (int r = 0; r < 4; ++r) {
        const int qg = q0 + cr + r;
        const float bv = bp[(size_t)qg * S_LEN + kg];
        const int mv = mp[(size_t)qg * S_LEN + kg];
        const float val = sc[nb][r] * 0.125f + bv;
        sc[nb][r] = (mv == 0) ? -1e9f : val;
      }
    }
    // ---- online softmax (rows live in lanes sharing l>>4; reduce over bits 0..3) ----
#pragma unroll
    for (int r = 0; r < 4; ++r) {
      float v = fmaxf(fmaxf(sc[0][r], sc[1][r]), fmaxf(sc[2][r], sc[3][r]));
      v = fmaxf(v, __shfl_xor(v, 1));
      v = fmaxf(v, __shfl_xor(v, 2));
      v = fmaxf(v, __shfl_xor(v, 4));
      v = fmaxf(v, __shfl_xor(v, 8));
      const float mn = fmaxf(m_run[r], v);
      const float corr = __expf(m_run[r] - mn);
      m_run[r] = mn;
      l_run[r] *= corr;
      cacc[0][r] *= corr; cacc[1][r] *= corr; cacc[2][r] *= corr; cacc[3][r] *= corr;
      float s0 = 0.f;
#pragma unroll
      for (int nb = 0; nb < 4; ++nb) {
        const float p = __expf(sc[nb][r] - mn);
        sc[nb][r] = p;
        s0 += p;
      }
      s0 += __shfl_xor(s0, 1);
      s0 += __shfl_xor(s0, 2);
      s0 += __shfl_xor(s0, 4);
      s0 += __shfl_xor(s0, 8);
      l_run[r] += s0;
    }
    // ---- P -> LDS (relayout C-layout -> A-layout) ----
    __syncthreads();
#pragma unroll
    for (int nb = 0; nb < 4; ++nb)
#pragma unroll
      for (int r = 0; r < 4; ++r)
        P[w][cr + r][nb * 16 + cc] = f2bf(sc[nb][r]);
    __syncthreads();
    bf16x8 pf0 = ld_bf8(&P[w][fr][fk]);
    bf16x8 pf1 = ld_bf8(&P[w][fr][32 + fk]);
    // ---- ctx += P V (V^T rows contiguous from global) ----
#pragma unroll
    for (int nd = 0; nd < 4; ++nd) {
      bf16x8 vf0 = ld_bf8(&Vp[(size_t)(nd * 16 + fr) * S_LEN + kt + fk]);
      bf16x8 vf1 = ld_bf8(&Vp[(size_t)(nd * 16 + fr) * S_LEN + kt + 32 + fk]);
      cacc[nd] = __builtin_amdgcn_mfma_f32_16x16x32_bf16(pf0, vf0, cacc[nd], 0, 0, 0);
      cacc[nd] = __builtin_amdgcn_mfma_f32_16x16x32_bf16(pf1, vf1, cacc[nd], 0, 0, 0);
    }
  }
  // ---- epilogue: ctx / l, write bf16 token-major ----
#pragma unroll
  for (int r = 0; r < 4; ++r) {
    const float inv = 1.0f / l_run[r];
    const int tok = b * S_LEN + q0 + cr + r;
    u16* cp = ctx + (size_t)tok * DM + h * DH;
#pragma unroll
    for (int nd = 0; nd < 4; ++nd)
      cp[nd * 16 + cc] = f2bf(cacc[nd][r] * inv);
  }
}

extern "C" void kernel_launch(void* const* d_in, const int* in_sizes, int n_in,
                              void* d_out, int out_size, void* d_ws, size_t ws_size,
                              hipStream_t stream) {
  const float* q   = (const float*)d_in[0];
  const float* k   = (const float*)d_in[1];
  const float* v   = (const float*)d_in[2];
  const int*   msk = (const int*)d_in[3];
  const float* pb  = (const float*)d_in[4];
  const float* w_q = (const float*)d_in[5];
  const float* b_q = (const float*)d_in[6];
  const float* w_k = (const float*)d_in[7];
  const float* b_k = (const float*)d_in[8];
  const float* w_v = (const float*)d_in[9];
  const float* b_v = (const float*)d_in[10];
  const float* w_o = (const float*)d_in[11];
  const float* b_o = (const float*)d_in[12];
  float* out = (float*)d_out;

  char* ws = (char*)d_ws;
  u16* wq_bf = (u16*)(ws + ((size_t)0 << 20));
  u16* wk_bf = (u16*)(ws + ((size_t)2 << 20));
  u16* wv_bf = (u16*)(ws + ((size_t)4 << 20));
  u16* wo_bf = (u16*)(ws + ((size_t)6 << 20));
  u16* x_bf  = (u16*)(ws + ((size_t)8 << 20));   // 8MB staging; reused as ctx
  u16* Qb    = (u16*)(ws + ((size_t)16 << 20));
  u16* Kb    = (u16*)(ws + ((size_t)24 << 20));
  u16* Vtb   = (u16*)(ws + ((size_t)32 << 20));

  dim3 blk(256);
  const int n4w = DM * DM / 4;
  const int n4x = MTOK * DM / 4;
  k_convert<<<dim3(1024), blk, 0, stream>>>(w_q, wq_bf, n4w);
  k_convert<<<dim3(1024), blk, 0, stream>>>(w_k, wk_bf, n4w);
  k_convert<<<dim3(1024), blk, 0, stream>>>(w_v, wv_bf, n4w);
  k_convert<<<dim3(1024), blk, 0, stream>>>(w_o, wo_bf, n4w);

  dim3 gg(32, 8);
  k_convert<<<dim3(2048), blk, 0, stream>>>(q, x_bf, n4x);
  k_gemm<0><<<gg, blk, 0, stream>>>(x_bf, wq_bf, b_q, Qb);
  k_convert<<<dim3(2048), blk, 0, stream>>>(k, x_bf, n4x);
  k_gemm<0><<<gg, blk, 0, stream>>>(x_bf, wk_bf, b_k, Kb);
  k_convert<<<dim3(2048), blk, 0, stream>>>(v, x_bf, n4x);
  k_gemm<1><<<gg, blk, 0, stream>>>(x_bf, wv_bf, b_v, Vtb);

  k_attn<<<dim3(64, 16), blk, 0, stream>>>(Qb, Kb, Vtb, pb, msk, x_bf);
  k_gemm<2><<<gg, blk, 0, stream>>>(x_bf, wo_bf, b_o, out);
}